// Round 6
// baseline (124.312 us; speedup 1.0000x reference)
//
#include <hip/hip_runtime.h>
#include <hip/hip_fp16.h>
#include <math.h>

#define BN 8192
#define NT 512
#define NW (NT / 64)
#define NGRP 4                 // 4 float4-groups/thread: 4*512*4 = 8192
#define INV_TAU (1.0f / 0.07f)
#define COFF 40.0f             // fixed softmax offset (replaces row max; exact math)
#define K2F 20.609929156f      // INV_TAU * log2(e)
#define C2F 57.707801636f      // COFF   * log2(e)

struct WsLayout {
  double bins_pu[64];   // per-row PU losses, binned
  double bins_ir[64];   // infonce row part
  double bins_ic[64];   // infonce col part
  double acc_prior;     // sum (pi_a - pi_ext)^2
  int P_tot, RN_tot;
  float A_tot;          // sum of (half-rounded) alphas over label==1
  float w_inf, w_pu, w_prior;
};

// ---------------- prep (32 blocks): stats via wave atomics + packed selector code --------
// code[j] = half2 { v, q } : v = alpha (pos) | -beta (rn) | 0 ; q = 1 if unlabeled else 0
__global__ void prep_kernel(const int* __restrict__ labels, const float* __restrict__ alphas,
                            const float* __restrict__ betas, const float* __restrict__ pia,
                            const float* __restrict__ pie, const int* __restrict__ epoch_p,
                            WsLayout* __restrict__ ws, __half2* __restrict__ code) {
  const int j = blockIdx.x * 256 + threadIdx.x;   // 32 * 256 = 8192
  const int l = labels[j];
  const bool isp = (l == 1), isrn = (l == -1);
  const float v = isp ? alphas[j] : (isrn ? -betas[j] : 0.f);
  const __half vh = __float2half(v);
  code[j] = __halves2half2(vh, __float2half((!isp && !isrn) ? 1.f : 0.f));
  int p = isp ? 1 : 0, rn = isrn ? 1 : 0;
  float a = isp ? __half2float(vh) : 0.f;         // A_tot from the SAME rounded alphas
  const float d = pia[j] - pie[j];
  float pr = d * d;
#pragma unroll
  for (int off = 32; off > 0; off >>= 1) {
    p  += __shfl_xor(p, off);
    rn += __shfl_xor(rn, off);
    a  += __shfl_xor(a, off);
    pr += __shfl_xor(pr, off);
  }
  if ((threadIdx.x & 63) == 0) {
    atomicAdd(&ws->P_tot, p);
    atomicAdd(&ws->RN_tot, rn);
    atomicAdd(&ws->A_tot, a);
    atomicAdd(&ws->acc_prior, (double)pr);
  }
  if (blockIdx.x == 0 && threadIdx.x == 0) {
    const int ep = epoch_p[0];
    float w_inf, w_pu, w_prior;
    if (ep < 5) { w_inf = 1.f; w_pu = 0.f; w_prior = 0.f; }
    else {
      const float puw = (ep >= 15) ? 1.f : (float)(ep - 5) / 10.f;
      w_inf = 1.f - puw; w_pu = puw; w_prior = (ep >= 15) ? 1.f : 0.f;
    }
    ws->w_inf = w_inf; ws->w_pu = w_pu; ws->w_prior = w_prior;
  }
}

// ---------------- per-row PU loss + gated infonce row LSE ----------------
// 12 hoisted float4 loads per thread, interleaved issue order (s,w,c per group)
// so group `it` compute can start after load 3*it+2 returns (progressive vmcnt).
__launch_bounds__(NT, 4)
__global__ void row_kernel(const float* __restrict__ sim, const float* __restrict__ pw,
                           const __half2* __restrict__ code, const float* __restrict__ pia,
                           WsLayout* __restrict__ ws) {
  const int row = blockIdx.x;
  const float w_pu = ws->w_pu, w_inf = ws->w_inf;
  if (w_pu == 0.0f && w_inf == 0.0f) return;
  const bool do_pu = (w_pu != 0.0f);

  const float4* __restrict__ sim4 = (const float4*)(sim + (size_t)row * BN);
  const float4* __restrict__ cd4  = (const float4*)code;
  const float4* __restrict__ pwp  = do_pu ? (const float4*)(pw + (size_t)row * BN) : sim4;

  // ---- hoisted interleaved loads: 12 outstanding float4 per thread ----
  float4 s4[NGRP], w4[NGRP], c4[NGRP];
#pragma unroll
  for (int it = 0; it < NGRP; ++it) {
    const int v = threadIdx.x + it * NT;
    s4[it] = sim4[v];
    w4[it] = pwp[v];
    c4[it] = cd4[v];
  }

  float se = 0.f, sp = 0.f, srn = 0.f, su = 0.f, sas = 0.f;
#pragma unroll
  for (int it = 0; it < NGRP; ++it) {
    const float sv[4] = {s4[it].x, s4[it].y, s4[it].z, s4[it].w};
    const float wv[4] = {w4[it].x, w4[it].y, w4[it].z, w4[it].w};
    const float cf[4] = {c4[it].x, c4[it].y, c4[it].z, c4[it].w};
#pragma unroll
    for (int c = 0; c < 4; ++c) {
      const __half2 h = __builtin_bit_cast(__half2, cf[c]);
      const float2 f = __half22float2(h);     // f.x = v (+alpha/-beta/0), f.y = q (1 if u)
      const float s = sv[c];
      const float ex = exp2f(fmaf(s, K2F, -C2F));   // = exp(s/tau - COFF)
      se += ex;
      const float we = wv[c] * ex;
      sp += (f.x > 0.f) ? ex : 0.f;
      su  = fmaf(f.y, we, su);
      srn = fmaf(fmaxf(-f.x, 0.f), we, srn);
      sas = fmaf(fmaxf(f.x, 0.f), s, sas);
    }
  }

  const int wid = threadIdx.x >> 6;
  const int lane = threadIdx.x & 63;
#pragma unroll
  for (int off = 32; off > 0; off >>= 1) {
    se  += __shfl_xor(se, off);
    sp  += __shfl_xor(sp, off);
    srn += __shfl_xor(srn, off);
    su  += __shfl_xor(su, off);
    sas += __shfl_xor(sas, off);
  }
  __shared__ float red[NW][8];
  if (lane == 0) {
    red[wid][0] = se; red[wid][1] = sp; red[wid][2] = srn;
    red[wid][3] = su; red[wid][4] = sas;
  }
  __syncthreads();

  if (threadIdx.x == 0) {
    double Se = 0.0, Sp = 0.0, Sr = 0.0, Su = 0.0, Sa = 0.0;
#pragma unroll
    for (int w = 0; w < NW; ++w) {
      Se += (double)red[w][0]; Sp += (double)red[w][1]; Sr += (double)red[w][2];
      Su += (double)red[w][3]; Sa += (double)red[w][4];
    }
    // diagonal contributions (self-exclusion in closed form); row is cache-hot
    const float s_rr = sim[(size_t)row * BN + row];
    const float l_rr = s_rr * INV_TAU;
    const float ex_rr_f = exp2f(fmaf(s_rr, K2F, -C2F));  // same fp as loop -> exact cancel
    const double ex_rr = (double)ex_rr_f;
    const float2 fr = __half22float2(code[row]);
    const bool rp = fr.x > 0.f, rrn = fr.x < 0.f, ru = fr.y > 0.5f;
    const float asr = fmaxf(fr.x, 0.f);
    const float rbr = fmaxf(-fr.x, 0.f);

    const double se_ex = fmax(Se - ex_rr, 1e-300);
    const double logZ = (double)COFF + log(se_ex);

    if (do_pu) {
      const float pw_rr = pw[(size_t)row * BN + row];
      const int P_tot = ws->P_tot, RN_tot = ws->RN_tot;
      const int U_tot = BN - P_tot - RN_tot;
      const int cp  = P_tot  - (rp ? 1 : 0);
      const int crn = RN_tot - (rrn ? 1 : 0);
      const int cu  = U_tot  - (ru ? 1 : 0);
      const double Apos  = (double)ws->A_tot - (double)asr;
      const double SaL   = (double)INV_TAU * Sa - (double)asr * (double)l_rr;
      const double sp_ex = Sp - (rp ? ex_rr : 0.0);
      const double sr_ex = Sr - (double)rbr * (double)pw_rr * ex_rr;
      const double su_ex = Su - (ru ? (double)pw_rr * ex_rr : 0.0);

      const double Lpos = (cp > 0) ? (-(SaL - logZ * Apos) / cp) : 0.0;
      const double Lrn  = (crn > 0) ? ((sr_ex / se_ex) / crn) : 0.0;
      const double EU = (su_ex / se_ex) / (cu > 0 ? cu : 1);
      const double EP = (sp_ex / se_ex) / (cp > 0 ? cp : 1);
      double pi = (double)pia[row];
      pi = pi < 1e-4 ? 1e-4 : (pi > 0.5 ? 0.5 : pi);
      const double deb = (EU - pi * EP) / (1.0 - pi + 1e-8);
      const double Lu = (cu > 0 && cp > 0) ? (deb > 0.0 ? deb : 0.0) : 0.0;
      atomicAdd(&ws->bins_pu[row & 63], Lpos + Lrn + Lu);
    }
    if (w_inf != 0.0f) {
      const double logZf = (double)COFF + log(Se);   // full row LSE (self included)
      atomicAdd(&ws->bins_ir[row & 63], logZf - (double)l_rr);
    }
  }
}

// ---------------- infonce column LSE (only active when epoch < PHASE2_END) ----------------
#define COL_BLKS 256
#define COLS_PER_BLK (BN / COL_BLKS)
__launch_bounds__(256)
__global__ void col_kernel(const float* __restrict__ sim, WsLayout* __restrict__ ws) {
  if (ws->w_inf == 0.0f) return;
  for (int k = 0; k < COLS_PER_BLK; ++k) {
    const int col = blockIdx.x * COLS_PER_BLK + k;
    float m = -3.0e38f, se = 0.f, diag = 0.f;
    for (int r = threadIdx.x; r < BN; r += 256) {
      const float l = sim[(size_t)r * BN + col] * INV_TAU;
      if (r == col) diag = l;
      if (l > m) { se *= __expf(m - l); m = l; }
      se += __expf(l - m);
    }
#pragma unroll
    for (int off = 32; off > 0; off >>= 1) {
      const float m2 = __shfl_xor(m, off), se2 = __shfl_xor(se, off);
      diag += __shfl_xor(diag, off);
      const float mn = fmaxf(m, m2);
      se = se * __expf(m - mn) + se2 * __expf(m2 - mn);
      m = mn;
    }
    __shared__ float red[4][3];
    const int wid = threadIdx.x >> 6;
    const int lane = threadIdx.x & 63;
    if (lane == 0) { red[wid][0] = m; red[wid][1] = se; red[wid][2] = diag; }
    __syncthreads();
    if (threadIdx.x == 0) {
      float M = red[0][0], Se = red[0][1], Dg = red[0][2];
      for (int w = 1; w < 4; ++w) {
        const float mn = fmaxf(M, red[w][0]);
        Se = Se * __expf(M - mn) + red[w][1] * __expf(red[w][0] - mn);
        M = mn;
        Dg += red[w][2];
      }
      const double logZf = (double)M + log((double)Se);
      atomicAdd(&ws->bins_ic[col & 63], logZf - (double)Dg);
    }
    __syncthreads();
  }
}

// ---------------- final combine ----------------
__global__ void final_kernel(const WsLayout* __restrict__ ws, float* __restrict__ out) {
  const int t = threadIdx.x;  // 64 threads
  double pu = ws->bins_pu[t];
  double ir = ws->bins_ir[t];
  double ic = ws->bins_ic[t];
#pragma unroll
  for (int off = 32; off > 0; off >>= 1) {
    pu += __shfl_xor(pu, off);
    ir += __shfl_xor(ir, off);
    ic += __shfl_xor(ic, off);
  }
  if (t == 0) {
    const double loss_pu  = pu / (double)BN;
    const double loss_inf = (ir + ic) / (2.0 * (double)BN);
    const double prior    = ws->acc_prior / (double)BN;
    const double total = (double)ws->w_inf * loss_inf
                       + (double)ws->w_pu * loss_pu
                       + (double)ws->w_prior * 0.1 * prior;
    out[0] = (float)total;
  }
}

extern "C" void kernel_launch(void* const* d_in, const int* in_sizes, int n_in,
                              void* d_out, int out_size, void* d_ws, size_t ws_size,
                              hipStream_t stream) {
  const float* sim    = (const float*)d_in[0];
  const int*   labels = (const int*)d_in[1];
  const float* alphas = (const float*)d_in[2];
  const float* betas  = (const float*)d_in[3];
  const float* pia    = (const float*)d_in[4];
  const float* pw     = (const float*)d_in[5];
  const float* pie    = (const float*)d_in[6];
  const int*   epoch  = (const int*)d_in[7];
  WsLayout* ws = (WsLayout*)d_ws;
  __half2* code = (__half2*)((char*)d_ws + 4096);
  float* out = (float*)d_out;

  hipMemsetAsync(d_ws, 0, 2048, stream);   // zero accumulator header (graph-capturable)
  hipLaunchKernelGGL(prep_kernel, dim3(32), dim3(256), 0, stream,
                     labels, alphas, betas, pia, pie, epoch, ws, code);
  hipLaunchKernelGGL(row_kernel, dim3(BN), dim3(NT), 0, stream,
                     sim, pw, code, pia, ws);
  hipLaunchKernelGGL(col_kernel, dim3(COL_BLKS), dim3(256), 0, stream, sim, ws);
  hipLaunchKernelGGL(final_kernel, dim3(1), dim3(64), 0, stream, ws, out);
}

// Round 7
// 108.217 us; speedup vs baseline: 1.1487x; 1.1487x over previous
//
#include <hip/hip_runtime.h>
#include <hip/hip_fp16.h>
#include <math.h>

#define BN 8192
#define NT 512
#define NW (NT / 64)
#define NGRP 4                 // 4 float4-groups/thread: 4*512*4 = 8192
#define INV_TAU (1.0f / 0.07f)
#define COFF 40.0f             // fixed softmax offset (replaces row max; exact math)
#define K2F 20.609929156f      // INV_TAU * log2(e)
#define C2F 57.707801636f      // COFF   * log2(e)
#define NPB 32                 // prep blocks

// Plain-store workspace: no zero-init required anywhere.
struct Header {
  int   part_P[NPB];
  int   part_RN[NPB];
  float part_A[NPB];
  float part_prior[NPB];
  float w_inf, w_pu, w_prior;
};
// ws offsets (bytes): header @0 | code @4096 (32KB) | loss_pu @40960 (32KB)
//                     ir @73728 (32KB) | ic @106496 (32KB)

// ---------------- prep (32 blocks): per-block partial stats + packed selector code --------
// code[j] = half2 { v, q } : v = alpha (pos) | -beta (rn) | 0 ; q = 1 if unlabeled else 0
__global__ void prep_kernel(const int* __restrict__ labels, const float* __restrict__ alphas,
                            const float* __restrict__ betas, const float* __restrict__ pia,
                            const float* __restrict__ pie, const int* __restrict__ epoch_p,
                            Header* __restrict__ hd, __half2* __restrict__ code) {
  const int j = blockIdx.x * 256 + threadIdx.x;   // 32 * 256 = 8192
  const int l = labels[j];
  const bool isp = (l == 1), isrn = (l == -1);
  const float v = isp ? alphas[j] : (isrn ? -betas[j] : 0.f);
  const __half vh = __float2half(v);
  code[j] = __halves2half2(vh, __float2half((!isp && !isrn) ? 1.f : 0.f));
  int p = isp ? 1 : 0, rn = isrn ? 1 : 0;
  float a = isp ? __half2float(vh) : 0.f;         // A_tot from the SAME rounded alphas
  const float d = pia[j] - pie[j];
  float pr = d * d;
#pragma unroll
  for (int off = 32; off > 0; off >>= 1) {
    p  += __shfl_xor(p, off);
    rn += __shfl_xor(rn, off);
    a  += __shfl_xor(a, off);
    pr += __shfl_xor(pr, off);
  }
  __shared__ int sp_[4], srn_[4];
  __shared__ float sa_[4], spr_[4];
  const int wid = threadIdx.x >> 6;
  if ((threadIdx.x & 63) == 0) { sp_[wid] = p; srn_[wid] = rn; sa_[wid] = a; spr_[wid] = pr; }
  __syncthreads();
  if (threadIdx.x == 0) {
    int P = 0, RN = 0; float A = 0.f, PR = 0.f;
#pragma unroll
    for (int w = 0; w < 4; ++w) { P += sp_[w]; RN += srn_[w]; A += sa_[w]; PR += spr_[w]; }
    hd->part_P[blockIdx.x] = P;
    hd->part_RN[blockIdx.x] = RN;
    hd->part_A[blockIdx.x] = A;
    hd->part_prior[blockIdx.x] = PR;
    if (blockIdx.x == 0) {
      const int ep = epoch_p[0];
      float w_inf, w_pu, w_prior;
      if (ep < 5) { w_inf = 1.f; w_pu = 0.f; w_prior = 0.f; }
      else {
        const float puw = (ep >= 15) ? 1.f : (float)(ep - 5) / 10.f;
        w_inf = 1.f - puw; w_pu = puw; w_prior = (ep >= 15) ? 1.f : 0.f;
      }
      hd->w_inf = w_inf; hd->w_pu = w_pu; hd->w_prior = w_prior;
    }
  }
}

// ---------------- per-row PU loss + gated infonce row LSE ----------------
// Round-4 proven geometry: 12 hoisted float4 loads (grouped by stream), branch-free loop.
__launch_bounds__(NT, 4)
__global__ void row_kernel(const float* __restrict__ sim, const float* __restrict__ pw,
                           const __half2* __restrict__ code, const float* __restrict__ pia,
                           const Header* __restrict__ hd, float* __restrict__ loss_pu,
                           float* __restrict__ ir) {
  const int row = blockIdx.x;
  const float w_pu = hd->w_pu, w_inf = hd->w_inf;
  if (w_pu == 0.0f && w_inf == 0.0f) return;
  const bool do_pu = (w_pu != 0.0f);

  const float4* __restrict__ sim4 = (const float4*)(sim + (size_t)row * BN);
  const float4* __restrict__ cd4  = (const float4*)code;
  const float4* __restrict__ pwp  = do_pu ? (const float4*)(pw + (size_t)row * BN) : sim4;

  // ---- hoisted loads: 12 outstanding float4 per thread (grouped order, r4-proven) ----
  float4 s4[NGRP], w4[NGRP], c4[NGRP];
#pragma unroll
  for (int it = 0; it < NGRP; ++it) s4[it] = sim4[threadIdx.x + it * NT];
#pragma unroll
  for (int it = 0; it < NGRP; ++it) w4[it] = pwp[threadIdx.x + it * NT];
#pragma unroll
  for (int it = 0; it < NGRP; ++it) c4[it] = cd4[threadIdx.x + it * NT];

  float se = 0.f, sp = 0.f, srn = 0.f, su = 0.f, sas = 0.f;
#pragma unroll
  for (int it = 0; it < NGRP; ++it) {
    const float sv[4] = {s4[it].x, s4[it].y, s4[it].z, s4[it].w};
    const float wv[4] = {w4[it].x, w4[it].y, w4[it].z, w4[it].w};
    const float cf[4] = {c4[it].x, c4[it].y, c4[it].z, c4[it].w};
#pragma unroll
    for (int c = 0; c < 4; ++c) {
      const __half2 h = __builtin_bit_cast(__half2, cf[c]);
      const float2 f = __half22float2(h);     // f.x = v (+alpha/-beta/0), f.y = q (1 if u)
      const float s = sv[c];
      const float ex = exp2f(fmaf(s, K2F, -C2F));   // = exp(s/tau - COFF)
      se += ex;
      const float we = wv[c] * ex;
      sp += (f.x > 0.f) ? ex : 0.f;
      su  = fmaf(f.y, we, su);
      srn = fmaf(fmaxf(-f.x, 0.f), we, srn);
      sas = fmaf(fmaxf(f.x, 0.f), s, sas);
    }
  }

  const int wid = threadIdx.x >> 6;
  const int lane = threadIdx.x & 63;
#pragma unroll
  for (int off = 32; off > 0; off >>= 1) {
    se  += __shfl_xor(se, off);
    sp  += __shfl_xor(sp, off);
    srn += __shfl_xor(srn, off);
    su  += __shfl_xor(su, off);
    sas += __shfl_xor(sas, off);
  }
  __shared__ float red[NW][8];
  if (lane == 0) {
    red[wid][0] = se; red[wid][1] = sp; red[wid][2] = srn;
    red[wid][3] = su; red[wid][4] = sas;
  }
  __syncthreads();

  if (threadIdx.x == 0) {
    double Se = 0.0, Sp = 0.0, Sr = 0.0, Su = 0.0, Sa = 0.0;
#pragma unroll
    for (int w = 0; w < NW; ++w) {
      Se += (double)red[w][0]; Sp += (double)red[w][1]; Sr += (double)red[w][2];
      Su += (double)red[w][3]; Sa += (double)red[w][4];
    }
    // diagonal contributions (self-exclusion in closed form); row is cache-hot
    const float s_rr = sim[(size_t)row * BN + row];
    const float l_rr = s_rr * INV_TAU;
    const float ex_rr_f = exp2f(fmaf(s_rr, K2F, -C2F));  // same fp as loop -> exact cancel
    const double ex_rr = (double)ex_rr_f;
    const float2 fr = __half22float2(code[row]);
    const bool rp = fr.x > 0.f, rrn = fr.x < 0.f, ru = fr.y > 0.5f;
    const float asr = fmaxf(fr.x, 0.f);
    const float rbr = fmaxf(-fr.x, 0.f);

    const double se_ex = fmax(Se - ex_rr, 1e-300);
    const double logZ = (double)COFF + log(se_ex);

    if (do_pu) {
      // inline partial-stat reduce (32 slots, L2-hot)
      int P_tot = 0, RN_tot = 0; float A_tot = 0.f;
#pragma unroll
      for (int b = 0; b < NPB; ++b) {
        P_tot += hd->part_P[b]; RN_tot += hd->part_RN[b]; A_tot += hd->part_A[b];
      }
      const float pw_rr = pw[(size_t)row * BN + row];
      const int U_tot = BN - P_tot - RN_tot;
      const int cp  = P_tot  - (rp ? 1 : 0);
      const int crn = RN_tot - (rrn ? 1 : 0);
      const int cu  = U_tot  - (ru ? 1 : 0);
      const double Apos  = (double)A_tot - (double)asr;
      const double SaL   = (double)INV_TAU * Sa - (double)asr * (double)l_rr;
      const double sp_ex = Sp - (rp ? ex_rr : 0.0);
      const double sr_ex = Sr - (double)rbr * (double)pw_rr * ex_rr;
      const double su_ex = Su - (ru ? (double)pw_rr * ex_rr : 0.0);

      const double Lpos = (cp > 0) ? (-(SaL - logZ * Apos) / cp) : 0.0;
      const double Lrn  = (crn > 0) ? ((sr_ex / se_ex) / crn) : 0.0;
      const double EU = (su_ex / se_ex) / (cu > 0 ? cu : 1);
      const double EP = (sp_ex / se_ex) / (cp > 0 ? cp : 1);
      double pi = (double)pia[row];
      pi = pi < 1e-4 ? 1e-4 : (pi > 0.5 ? 0.5 : pi);
      const double deb = (EU - pi * EP) / (1.0 - pi + 1e-8);
      const double Lu = (cu > 0 && cp > 0) ? (deb > 0.0 ? deb : 0.0) : 0.0;
      loss_pu[row] = (float)(Lpos + Lrn + Lu);
    }
    if (w_inf != 0.0f) {
      const double logZf = (double)COFF + log(Se);   // full row LSE (self included)
      ir[row] = (float)(logZf - (double)l_rr);
    }
  }
}

// ---------------- infonce column LSE (only active when epoch < PHASE2_END) ----------------
#define COL_BLKS 256
#define COLS_PER_BLK (BN / COL_BLKS)
__launch_bounds__(256)
__global__ void col_kernel(const float* __restrict__ sim, const Header* __restrict__ hd,
                           float* __restrict__ ic) {
  if (hd->w_inf == 0.0f) return;
  for (int k = 0; k < COLS_PER_BLK; ++k) {
    const int col = blockIdx.x * COLS_PER_BLK + k;
    float m = -3.0e38f, se = 0.f, diag = 0.f;
    for (int r = threadIdx.x; r < BN; r += 256) {
      const float l = sim[(size_t)r * BN + col] * INV_TAU;
      if (r == col) diag = l;
      if (l > m) { se *= __expf(m - l); m = l; }
      se += __expf(l - m);
    }
#pragma unroll
    for (int off = 32; off > 0; off >>= 1) {
      const float m2 = __shfl_xor(m, off), se2 = __shfl_xor(se, off);
      diag += __shfl_xor(diag, off);
      const float mn = fmaxf(m, m2);
      se = se * __expf(m - mn) + se2 * __expf(m2 - mn);
      m = mn;
    }
    __shared__ float red[4][3];
    const int wid = threadIdx.x >> 6;
    const int lane = threadIdx.x & 63;
    if (lane == 0) { red[wid][0] = m; red[wid][1] = se; red[wid][2] = diag; }
    __syncthreads();
    if (threadIdx.x == 0) {
      float M = red[0][0], Se = red[0][1], Dg = red[0][2];
      for (int w = 1; w < 4; ++w) {
        const float mn = fmaxf(M, red[w][0]);
        Se = Se * __expf(M - mn) + red[w][1] * __expf(red[w][0] - mn);
        M = mn;
        Dg += red[w][2];
      }
      ic[col] = (float)((double)M + log((double)Se) - (double)Dg);
    }
    __syncthreads();
  }
}

// ---------------- final combine: reduce per-row losses (L2-resident) ----------------
__launch_bounds__(256)
__global__ void final_kernel(const Header* __restrict__ hd, const float* __restrict__ loss_pu,
                             const float* __restrict__ ir, const float* __restrict__ ic,
                             float* __restrict__ out) {
  const int t = threadIdx.x;  // 256
  const float w_inf = hd->w_inf, w_pu = hd->w_pu, w_prior = hd->w_prior;
  double pu = 0.0, irs = 0.0, ics = 0.0;
  if (w_pu != 0.0f)
    for (int j = t; j < BN; j += 256) pu += (double)loss_pu[j];
  if (w_inf != 0.0f)
    for (int j = t; j < BN; j += 256) { irs += (double)ir[j]; ics += (double)ic[j]; }
  double pr = (t < NPB) ? (double)hd->part_prior[t] : 0.0;
#pragma unroll
  for (int off = 32; off > 0; off >>= 1) {
    pu  += __shfl_xor(pu, off);
    irs += __shfl_xor(irs, off);
    ics += __shfl_xor(ics, off);
    pr  += __shfl_xor(pr, off);
  }
  __shared__ double red[4][4];
  const int wid = t >> 6, lane = t & 63;
  if (lane == 0) { red[wid][0] = pu; red[wid][1] = irs; red[wid][2] = ics; red[wid][3] = pr; }
  __syncthreads();
  if (t == 0) {
    double PU = 0, IR = 0, IC = 0, PR = 0;
#pragma unroll
    for (int w = 0; w < 4; ++w) { PU += red[w][0]; IR += red[w][1]; IC += red[w][2]; PR += red[w][3]; }
    double total = 0.0;
    if (w_pu != 0.0f)    total += (double)w_pu * (PU / (double)BN);
    if (w_inf != 0.0f)   total += (double)w_inf * ((IR + IC) / (2.0 * (double)BN));
    if (w_prior != 0.0f) total += (double)w_prior * 0.1 * (PR / (double)BN);
    out[0] = (float)total;
  }
}

extern "C" void kernel_launch(void* const* d_in, const int* in_sizes, int n_in,
                              void* d_out, int out_size, void* d_ws, size_t ws_size,
                              hipStream_t stream) {
  const float* sim    = (const float*)d_in[0];
  const int*   labels = (const int*)d_in[1];
  const float* alphas = (const float*)d_in[2];
  const float* betas  = (const float*)d_in[3];
  const float* pia    = (const float*)d_in[4];
  const float* pw     = (const float*)d_in[5];
  const float* pie    = (const float*)d_in[6];
  const int*   epoch  = (const int*)d_in[7];
  Header*  hd      = (Header*)d_ws;
  __half2* code    = (__half2*)((char*)d_ws + 4096);
  float*   loss_pu = (float*)((char*)d_ws + 40960);
  float*   ir      = (float*)((char*)d_ws + 73728);
  float*   ic      = (float*)((char*)d_ws + 106496);
  float*   out     = (float*)d_out;

  hipLaunchKernelGGL(prep_kernel, dim3(NPB), dim3(256), 0, stream,
                     labels, alphas, betas, pia, pie, epoch, hd, code);
  hipLaunchKernelGGL(row_kernel, dim3(BN), dim3(NT), 0, stream,
                     sim, pw, code, pia, hd, loss_pu, ir);
  hipLaunchKernelGGL(col_kernel, dim3(COL_BLKS), dim3(256), 0, stream, sim, hd, ic);
  hipLaunchKernelGGL(final_kernel, dim3(1), dim3(256), 0, stream, hd, loss_pu, ir, ic, out);
}